// Round 1
// baseline (278.745 us; speedup 1.0000x reference)
//
#include <hip/hip_runtime.h>
#include <math.h>

#define DM 512          // d_model
#define NQ 16           // num output queries
#define NG (NQ + 1)     // 16 score rows + 1 pooled-v row
#define NR (NG + 2)     // 19 partial rows: S1, S2, acc[0..16]

typedef __attribute__((ext_vector_type(2))) float f32x2;

__device__ __forceinline__ float wave_reduce_sum(float v) {
    #pragma unroll
    for (int off = 32; off > 0; off >>= 1) v += __shfl_xor(v, off, 64);
    return v;
}
__device__ __forceinline__ float wave_reduce_max(float v) {
    #pragma unroll
    for (int off = 32; off > 0; off >>= 1) v = fmaxf(v, __shfl_xor(v, off, 64));
    return v;
}

// --- K1: PET generation + fused query-LN -> qh ------------------------------
// blocks [0, (N/64)*16)         : PET[d][n] (trig)
// blocks [(N/64)*16, +NQ*DM/4)  : qh[q][e] = LN(query[q]*scale) . Wq[e] + bq[e]
//                                 (LN recomputed per wave, registers only)
__global__ void k_setup(const float* __restrict__ query,
                        const float* __restrict__ ln_q_w, const float* __restrict__ ln_q_b,
                        const float* __restrict__ Wq, const float* __restrict__ bq,
                        float* __restrict__ PET, float* __restrict__ qh, int N) {
    int lane = threadIdx.x & 63;
    int bx = blockIdx.x;
    int nt = N >> 6;
    int petBlocks = nt * 16;
    if (bx < petBlocks) {                 // --- PET ---
        int w = threadIdx.x >> 6;
        int ntile = bx % nt, jg = bx / nt;
        int n = ntile * 64 + lane;
        float p = (float)(N - 1 - n);     // reversed PE
        const float c = -logf(10000.f) / (float)DM;
        int jbase = jg * 16 + w * 4;
        #pragma unroll
        for (int u = 0; u < 4; ++u) {
            int j = jbase + u;
            float wj = expf((float)(2 * j) * c);
            float ang = p * wj;
            PET[(size_t)(2 * j) * N + n] = sinf(ang);
            PET[(size_t)(2 * j + 1) * N + n] = cosf(ang);
        }
    } else {                              // --- qh (one wave per (q,e)) ---
        int idx = (bx - petBlocks) * 4 + (threadIdx.x >> 6);   // 0..8191
        int q = idx >> 9, e = idx & 511;
        const float scale = 22.627416997969522f;   // sqrt(512)
        const float4* qr = (const float4*)(query + (size_t)q * DM);
        float4 a0 = qr[lane * 2], a1 = qr[lane * 2 + 1];
        a0.x *= scale; a0.y *= scale; a0.z *= scale; a0.w *= scale;
        a1.x *= scale; a1.y *= scale; a1.z *= scale; a1.w *= scale;
        float s  = a0.x + a0.y + a0.z + a0.w + a1.x + a1.y + a1.z + a1.w;
        float s2 = a0.x * a0.x + a0.y * a0.y + a0.z * a0.z + a0.w * a0.w
                 + a1.x * a1.x + a1.y * a1.y + a1.z * a1.z + a1.w * a1.w;
        s = wave_reduce_sum(s); s2 = wave_reduce_sum(s2);
        float m = s * (1.f / DM);
        float var = s2 * (1.f / DM) - m * m;
        float rstd = rsqrtf(var + 1e-5f);
        const float4* gw = (const float4*)ln_q_w;
        const float4* gb = (const float4*)ln_q_b;
        const float4* wr = (const float4*)(Wq + (size_t)e * DM);
        float4 w0 = gw[lane * 2], w1 = gw[lane * 2 + 1];
        float4 b0 = gb[lane * 2], b1 = gb[lane * 2 + 1];
        float4 W0 = wr[lane * 2], W1 = wr[lane * 2 + 1];
        float acc = ((a0.x - m) * rstd * w0.x + b0.x) * W0.x
                  + ((a0.y - m) * rstd * w0.y + b0.y) * W0.y
                  + ((a0.z - m) * rstd * w0.z + b0.z) * W0.z
                  + ((a0.w - m) * rstd * w0.w + b0.w) * W0.w
                  + ((a1.x - m) * rstd * w1.x + b1.x) * W1.x
                  + ((a1.y - m) * rstd * w1.y + b1.y) * W1.y
                  + ((a1.z - m) * rstd * w1.z + b1.z) * W1.z
                  + ((a1.w - m) * rstd * w1.w + b1.w) * W1.w;
        acc = wave_reduce_sum(acc);
        if (lane == 0) qh[q * DM + e] = acc + bq[e];
    }
}

// --- K2: one block per g (0..16): A2 row + consts ---------------------------
// g<16: qt[g,d] = sum_e qh[g,e]*Wk[e,d];  g==16: wv[d] = sum_e Wo[e]*Wv[e,d]
// A[g,d] = qt*lnw[d] (duplicated f32x2); consts[g]=sum_d A; consts[16+g]=
// sum_d qt*lnb + sum_e row*b (bk or bv). Direct Wk/Wv reads (no transpose).
__global__ void k_A(const float* __restrict__ qh, const float* __restrict__ Wk,
                    const float* __restrict__ Wv, const float* __restrict__ Wo,
                    const float* __restrict__ lnw, const float* __restrict__ lnb,
                    const float* __restrict__ bk, const float* __restrict__ bv,
                    f32x2* __restrict__ A2, float* __restrict__ consts) {
    __shared__ float xrow[DM];
    __shared__ float r4[3][4];
    int g = blockIdx.x;
    int tid = threadIdx.x;
    int lane = tid & 63, w = tid >> 6;
    const float* src = (g < NQ) ? (qh + (size_t)g * DM) : Wo;
    for (int i = tid; i < DM; i += 256) xrow[i] = src[i];
    __syncthreads();
    const float* W = (g < NQ) ? Wk : Wv;
    int d0 = tid, d1 = tid + 256;
    float acc0 = 0.f, acc1 = 0.f;
    #pragma unroll 8
    for (int e = 0; e < DM; ++e) {
        float xe = xrow[e];
        acc0 = fmaf(W[(size_t)e * DM + d0], xe, acc0);
        acc1 = fmaf(W[(size_t)e * DM + d1], xe, acc1);
    }
    float a0 = acc0 * lnw[d0], a1 = acc1 * lnw[d1];
    f32x2 p0; p0.x = a0; p0.y = a0;
    f32x2 p1; p1.x = a1; p1.y = a1;
    A2[(size_t)g * DM + d0] = p0;
    A2[(size_t)g * DM + d1] = p1;
    const float* bvec = (g < NQ) ? bk : bv;
    float sA = a0 + a1;
    float sL = acc0 * lnb[d0] + acc1 * lnb[d1];
    float sB = xrow[d0] * bvec[d0] + xrow[d1] * bvec[d1];
    sA = wave_reduce_sum(sA);
    sL = wave_reduce_sum(sL);
    sB = wave_reduce_sum(sB);
    if (lane == 0) { r4[0][w] = sA; r4[1][w] = sL; r4[2][w] = sB; }
    __syncthreads();
    if (tid == 0) {
        float SA = r4[0][0] + r4[0][1] + r4[0][2] + r4[0][3];
        float SL = r4[1][0] + r4[1][1] + r4[1][2] + r4[1][3];
        float SB = r4[2][0] + r4[2][1] + r4[2][2] + r4[2][3];
        if (g < NQ) { consts[g] = SA; consts[16 + g] = SL + SB; }
        else        { consts[32] = SA; consts[33] = SL + SB; }
    }
}

// --- K3: main streaming. y = scale*x + pe accumulated directly.
// One block per (ntile,b) covers the FULL 512-d range: 8 waves x 64 d.
// Rows: S1=sum y, S2=sum y^2, acc[g]=sum A[g,d]*y. Packed f32x2 math,
// A broadcast via duplicated A2 (uniform addr -> s_load). ~90 VGPR, no spill.
__launch_bounds__(512, 4)
__global__ void main3_kernel(const float* __restrict__ latents,
                             const float* __restrict__ PET,
                             const f32x2* __restrict__ A2,
                             float* __restrict__ pbuf, int N) {
    int ntile = blockIdx.x;
    int b = blockIdx.y;
    int lane = threadIdx.x & 63;
    int w = threadIdx.x >> 6;                 // 0..7
    int n0 = ntile * 128 + lane * 2;

    int d0 = __builtin_amdgcn_readfirstlane(w * 64);
    const float* latf = latents + (size_t)b * DM * N + (size_t)d0 * N + n0;
    const float* petf = PET + (size_t)d0 * N + n0;
    const float scale = 22.627416997969522f;
    f32x2 sc2; sc2.x = scale; sc2.y = scale;

    f32x2 acc[NG];
    #pragma unroll
    for (int i = 0; i < NG; ++i) { acc[i].x = 0.f; acc[i].y = 0.f; }
    f32x2 S1 = {0.f, 0.f}, S2 = {0.f, 0.f};

    const int U = 4;                 // d per chunk
    const int NC = 64 / U;           // 16 chunks
    f32x2 xb[2][U], pb[2][U];
    #pragma unroll
    for (int u = 0; u < U; ++u) {
        xb[0][u] = __builtin_nontemporal_load((const f32x2*)(latf + (size_t)u * N));
        pb[0][u] = *(const f32x2*)(petf + (size_t)u * N);
    }
    for (int c = 0; c < NC; c += 2) {         // explicit 2x unroll: cur/nxt static
        #pragma unroll
        for (int u = 0; u < U; ++u) {
            size_t dd = (size_t)((c + 1) * U + u) * N;
            xb[1][u] = __builtin_nontemporal_load((const f32x2*)(latf + dd));
            pb[1][u] = *(const f32x2*)(petf + dd);
        }
        #pragma unroll
        for (int u = 0; u < U; ++u) {
            f32x2 y = xb[0][u] * sc2 + pb[0][u];
            S1 += y; S2 += y * y;
            int d = d0 + c * U + u;
            #pragma unroll
            for (int q = 0; q < NG; ++q)
                acc[q] += A2[(size_t)q * DM + d] * y;
        }
        if (c + 2 < NC) {
            #pragma unroll
            for (int u = 0; u < U; ++u) {
                size_t dd = (size_t)((c + 2) * U + u) * N;
                xb[0][u] = __builtin_nontemporal_load((const f32x2*)(latf + dd));
                pb[0][u] = *(const f32x2*)(petf + dd);
            }
        }
        #pragma unroll
        for (int u = 0; u < U; ++u) {
            f32x2 y = xb[1][u] * sc2 + pb[1][u];
            S1 += y; S2 += y * y;
            int d = d0 + (c + 1) * U + u;
            #pragma unroll
            for (int q = 0; q < NG; ++q)
                acc[q] += A2[(size_t)q * DM + d] * y;
        }
    }

    // 8-wave -> 4-slot two-phase reduction (keeps static LDS at 38.9 KB)
    __shared__ f32x2 red[4][NR][64];
    if (w >= 4) {
        int ww = w - 4;
        red[ww][0][lane] = S1;
        red[ww][1][lane] = S2;
        #pragma unroll
        for (int i = 0; i < NG; ++i) red[ww][2 + i][lane] = acc[i];
    }
    __syncthreads();
    if (w < 4) {
        red[w][0][lane] += S1;
        red[w][1][lane] += S2;
        #pragma unroll
        for (int i = 0; i < NG; ++i) red[w][2 + i][lane] += acc[i];
    }
    __syncthreads();
    if (w == 0) {
        float* pout = pbuf + (size_t)b * NR * N + n0;
        #pragma unroll
        for (int i = 0; i < NR; ++i) {
            f32x2 t = red[0][i][lane] + red[1][i][lane]
                    + red[2][i][lane] + red[3][i][lane];
            *(f32x2*)(pout + (size_t)i * N) = t;
        }
    }
}

// --- K4: fused finalize + softmax, one block per batch b --------------------
// phase 1: per n-pair LN math -> scores[16][N] + v[N] in LDS
// phase 2: wave-per-row softmax from LDS, write attn + logits
__global__ void k_fin(const float* __restrict__ pbuf,
                      const float* __restrict__ consts,
                      const float* __restrict__ query_mask,
                      const float* __restrict__ bo,
                      float* __restrict__ out_logits,
                      float* __restrict__ out_attn, int N) {
    __shared__ float scs[NQ][512];
    __shared__ float vls[512];
    int b = blockIdx.x;
    int tid = threadIdx.x;
    const float isd = 0.044194173824159216f;  // 1/sqrt(512)
    float c32 = consts[32], c33 = consts[33];

    for (int np = tid; np < (N >> 1); np += 256) {
        int n0 = np * 2;
        const float* p = pbuf + (size_t)b * NR * N + n0;
        f32x2 t[NR];
        #pragma unroll
        for (int i = 0; i < NR; ++i) t[i] = *(const f32x2*)(p + (size_t)i * N);
        f32x2 m = t[0] * (1.f / DM);
        f32x2 ex2 = t[1] * (1.f / DM);
        f32x2 rstd;
        rstd.x = rsqrtf(ex2.x - m.x * m.x + 1e-5f);
        rstd.y = rsqrtf(ex2.y - m.y * m.y + 1e-5f);
        f32x2 v = rstd * (t[2 + NQ] - m * c32) + c33;
        *(f32x2*)&vls[n0] = v;
        #pragma unroll
        for (int q = 0; q < NQ; ++q) {
            f32x2 sc = (rstd * (t[2 + q] - m * consts[q]) + consts[16 + q]) * isd;
            *(f32x2*)&scs[q][n0] = sc;
        }
    }
    __syncthreads();

    int lane = tid & 63, w = tid >> 6;
    int nv = N >> 2;                      // float4 count per row
    for (int q = w; q < NQ; q += 4) {
        int r = b * NQ + q;
        float qm = query_mask[r];
        float4* arow = (float4*)(out_attn + (size_t)r * N);
        if (qm == 0.f) {                  // fully masked: uniform weights, wiped logits
            float u = 1.f / (float)N;
            float4 uv = make_float4(u, u, u, u);
            for (int i = lane; i < nv; i += 64) arow[i] = uv;
            if (lane == 0) out_logits[r] = bo[0];
            continue;
        }
        const float4* srow = (const float4*)scs[q];
        float4 sv[2];
        sv[0] = srow[lane]; sv[1] = srow[64 + lane];
        float mx = fmaxf(fmaxf(fmaxf(sv[0].x, sv[0].y), fmaxf(sv[0].z, sv[0].w)),
                         fmaxf(fmaxf(sv[1].x, sv[1].y), fmaxf(sv[1].z, sv[1].w)));
        mx = wave_reduce_max(mx);
        float sum = 0.f;
        #pragma unroll
        for (int i = 0; i < 2; ++i) {
            sv[i].x = expf(sv[i].x - mx); sv[i].y = expf(sv[i].y - mx);
            sv[i].z = expf(sv[i].z - mx); sv[i].w = expf(sv[i].w - mx);
            sum += sv[i].x + sv[i].y + sv[i].z + sv[i].w;
        }
        sum = wave_reduce_sum(sum);
        float inv = 1.f / sum;
        const float4* vrow = (const float4*)vls;
        float lp = 0.f;
        #pragma unroll
        for (int i = 0; i < 2; ++i) {
            float4 vv = vrow[i * 64 + lane];
            float4 wgt;
            wgt.x = sv[i].x * inv; wgt.y = sv[i].y * inv;
            wgt.z = sv[i].z * inv; wgt.w = sv[i].w * inv;
            arow[i * 64 + lane] = wgt;
            lp += wgt.x * vv.x + wgt.y * vv.y + wgt.z * vv.z + wgt.w * vv.w;
        }
        lp = wave_reduce_sum(lp);
        if (lane == 0) out_logits[r] = lp + bo[0];
    }
}

extern "C" void kernel_launch(void* const* d_in, const int* in_sizes, int n_in,
                              void* d_out, int out_size, void* d_ws, size_t ws_size,
                              hipStream_t stream) {
    const float* latents    = (const float*)d_in[0];
    const float* query_mask = (const float*)d_in[1];
    const float* query      = (const float*)d_in[2];
    const float* ln_lat_w   = (const float*)d_in[3];
    const float* ln_lat_b   = (const float*)d_in[4];
    const float* ln_q_w     = (const float*)d_in[5];
    const float* ln_q_b     = (const float*)d_in[6];
    const float* Wq         = (const float*)d_in[7];
    const float* bq         = (const float*)d_in[8];
    const float* Wk         = (const float*)d_in[9];
    const float* bk         = (const float*)d_in[10];
    const float* Wv         = (const float*)d_in[11];
    const float* bv         = (const float*)d_in[12];
    const float* Wo         = (const float*)d_in[13];
    const float* bo         = (const float*)d_in[14];

    int B = in_sizes[1] / NQ;
    int N = in_sizes[0] / (DM * B);

    float* ws = (float*)d_ws;
    size_t off = 0;
    float* PET    = ws + off; off += (size_t)DM * N;
    float* qh     = ws + off; off += NQ * DM;
    float* A2     = ws + off; off += (size_t)NG * DM * 2;
    float* consts = ws + off; off += 64;
    float* pbuf   = ws + off; off += (size_t)B * NR * N;

    float* out_logits = (float*)d_out;
    float* out_attn   = out_logits + (size_t)B * NQ;

    int petBlocks = (N >> 6) * 16;
    k_setup<<<petBlocks + NQ * DM / 4, 256, 0, stream>>>(
        query, ln_q_w, ln_q_b, Wq, bq, PET, qh, N);
    k_A<<<NG, 256, 0, stream>>>(qh, Wk, Wv, Wo, ln_lat_w, ln_lat_b, bk, bv,
                                (f32x2*)A2, consts);
    main3_kernel<<<dim3(N >> 7, B), 512, 0, stream>>>(latents, PET,
                                                      (const f32x2*)A2, pbuf, N);
    k_fin<<<B, 256, 0, stream>>>(pbuf, consts, query_mask, bo,
                                 out_logits, out_attn, N);
}

// Round 2
// 245.634 us; speedup vs baseline: 1.1348x; 1.1348x over previous
//
#include <hip/hip_runtime.h>
#include <math.h>

#define DM 512          // d_model
#define NQ 16           // num output queries
#define NG (NQ + 1)     // 16 score rows + 1 pooled-v row
#define NR (NG + 2)     // 19 partial rows: S1, S2, acc[0..16]

typedef __attribute__((ext_vector_type(2))) float f32x2;

__device__ __forceinline__ float wave_reduce_sum(float v) {
    #pragma unroll
    for (int off = 32; off > 0; off >>= 1) v += __shfl_xor(v, off, 64);
    return v;
}
__device__ __forceinline__ float wave_reduce_max(float v) {
    #pragma unroll
    for (int off = 32; off > 0; off >>= 1) v = fmaxf(v, __shfl_xor(v, off, 64));
    return v;
}

// --- K1: fused independent precompute --------------------------------------
// blocks 0..127   : PET[d][n] generation (8 n-tiles x 16 j-groups)
// blocks 128..255 : LDS-tiled transpose Wk->WkT, Wv->WvT
// block  256      : LayerNorm of query*scale (4 waves x 4 rows)
__global__ void k1_setup(const float* __restrict__ Wk, const float* __restrict__ Wv,
                         const float* __restrict__ query,
                         const float* __restrict__ ln_q_w, const float* __restrict__ ln_q_b,
                         float* __restrict__ PET, float* __restrict__ WkT,
                         float* __restrict__ WvT, float* __restrict__ q_ln, int N) {
    __shared__ float tile[64][65];
    int bx = blockIdx.x;
    int lane = threadIdx.x & 63;
    int w = threadIdx.x >> 6;

    if (bx < 128) {                       // --- PET ---
        int ntile = bx & 7, jg = bx >> 3;
        int n = ntile * 64 + lane;
        float p = (float)(N - 1 - n);     // reversed PE
        const float c = -logf(10000.f) / (float)DM;
        int jbase = jg * 16 + w * 4;
        #pragma unroll
        for (int u = 0; u < 4; ++u) {
            int j = jbase + u;
            float wj = expf((float)(2 * j) * c);
            float ang = p * wj;
            PET[(size_t)(2 * j) * N + n] = sinf(ang);
            PET[(size_t)(2 * j + 1) * N + n] = cosf(ang);
        }
    } else if (bx < 256) {                // --- transpose ---
        int t = bx - 128;
        const float* W = (t >> 6) ? Wv : Wk;
        float* WT = (t >> 6) ? WvT : WkT;
        int tl = t & 63;
        int te = tl >> 3, td = tl & 7;    // 8x8 tiles of 64x64
        #pragma unroll
        for (int i = 0; i < 16; ++i) {
            int el = w * 16 + i;
            tile[el][lane] = W[(size_t)(te * 64 + el) * DM + td * 64 + lane];
        }
        __syncthreads();
        #pragma unroll
        for (int i = 0; i < 16; ++i) {
            int dl = w * 16 + i;
            WT[(size_t)(td * 64 + dl) * DM + te * 64 + lane] = tile[lane][dl];
        }
    } else {                              // --- query LN ---
        const float scale = 22.627416997969522f;   // sqrt(512)
        for (int qi = 0; qi < 4; ++qi) {
            int q = w * 4 + qi;
            float vals[8], s = 0.f, s2 = 0.f;
            #pragma unroll
            for (int i = 0; i < 8; ++i) {
                float x = query[q * DM + i * 64 + lane] * scale;
                vals[i] = x; s += x; s2 += x * x;
            }
            s = wave_reduce_sum(s); s2 = wave_reduce_sum(s2);
            float m = s * (1.f / DM);
            float var = s2 * (1.f / DM) - m * m;
            float rstd = rsqrtf(var + 1e-5f);
            #pragma unroll
            for (int i = 0; i < 8; ++i) {
                int d = i * 64 + lane;
                q_ln[q * DM + d] = (vals[i] - m) * rstd * ln_q_w[d] + ln_q_b[d];
            }
        }
    }
}

// --- K2: qh[q][e] = q_ln[q] . Wq[e] + bq[e], one wave per output -----------
__global__ void k2_qh(const float* __restrict__ q_ln, const float* __restrict__ Wq,
                      const float* __restrict__ bq, float* __restrict__ qh) {
    int idx = blockIdx.x * 4 + (threadIdx.x >> 6);   // 0..8191
    int lane = threadIdx.x & 63;
    int q = idx >> 9, e = idx & 511;
    const float4* wr = (const float4*)(Wq + (size_t)e * DM);
    const float4* xr = (const float4*)(q_ln + (size_t)q * DM);
    float4 w0 = wr[lane * 2], w1 = wr[lane * 2 + 1];
    float4 x0 = xr[lane * 2], x1 = xr[lane * 2 + 1];
    float s = w0.x * x0.x + w0.y * x0.y + w0.z * x0.z + w0.w * x0.w
            + w1.x * x1.x + w1.y * x1.y + w1.z * x1.z + w1.w * x1.w;
    s = wave_reduce_sum(s);
    if (lane == 0) qh[q * DM + e] = s + bq[e];
}

// --- K3: qt[g][d] (g<16) and wv[d] (g=16) via contiguous WkT/WvT rows ------
//         A[g][d] = coeff * ln_lat_w[d]; A2 = duplicated pair for pk_fma ----
__global__ void k3_qt(const float* __restrict__ qh, const float* __restrict__ WkT,
                      const float* __restrict__ Wo, const float* __restrict__ WvT,
                      const float* __restrict__ lnw,
                      float* __restrict__ qt, float* __restrict__ A,
                      f32x2* __restrict__ A2, float* __restrict__ wvout) {
    int idx = blockIdx.x * 4 + (threadIdx.x >> 6);   // 0..8703
    int lane = threadIdx.x & 63;
    int g = idx >> 9, d = idx & 511;
    const float4* wr;
    const float4* xr;
    if (g < NQ) {
        wr = (const float4*)(WkT + (size_t)d * DM);
        xr = (const float4*)(qh + (size_t)g * DM);
    } else {
        wr = (const float4*)(WvT + (size_t)d * DM);
        xr = (const float4*)Wo;
    }
    float4 w0 = wr[lane * 2], w1 = wr[lane * 2 + 1];
    float4 x0 = xr[lane * 2], x1 = xr[lane * 2 + 1];
    float s = w0.x * x0.x + w0.y * x0.y + w0.z * x0.z + w0.w * x0.w
            + w1.x * x1.x + w1.y * x1.y + w1.z * x1.z + w1.w * x1.w;
    s = wave_reduce_sum(s);
    if (lane == 0) {
        if (g < NQ) qt[g * DM + d] = s;
        else wvout[d] = s;
        float a = s * lnw[d];
        A[g * DM + d] = a;
        f32x2 ap; ap.x = a; ap.y = a;
        A2[g * DM + d] = ap;
    }
}

// --- K4: consts only (5 blocks, wave-tasks). peA/peS/peQ are gone: the
// y = scale*x + pe refold in main makes them algebraically redundant. -------
__global__ void k_consts(const float* __restrict__ A, const float* __restrict__ qt,
                         const float* __restrict__ qh, const float* __restrict__ wv,
                         const float* __restrict__ lnb, const float* __restrict__ bk,
                         const float* __restrict__ Wo, const float* __restrict__ bv,
                         float* __restrict__ consts) {
    int lane = threadIdx.x & 63;
    int w = threadIdx.x >> 6;
    int t = blockIdx.x * 4 + w;           // 0..19, valid 0..16
    if (t > NQ) return;
    if (t < NQ) {
        float sa = 0.f, sc = 0.f, qb = 0.f;
        #pragma unroll
        for (int i = 0; i < 8; ++i) {
            int d = i * 64 + lane;
            sa += A[t * DM + d];
            sc = fmaf(qt[t * DM + d], lnb[d], sc);
            qb = fmaf(qh[t * DM + d], bk[d], qb);
        }
        sa = wave_reduce_sum(sa);
        sc = wave_reduce_sum(sc);
        qb = wave_reduce_sum(qb);
        if (lane == 0) { consts[t] = sa; consts[16 + t] = sc + qb; }
    } else {
        float sa = 0.f, cv = 0.f, bvo = 0.f;
        #pragma unroll
        for (int i = 0; i < 8; ++i) {
            int d = i * 64 + lane;
            sa += A[NQ * DM + d];
            cv = fmaf(wv[d], lnb[d], cv);
            bvo = fmaf(Wo[d], bv[d], bvo);
        }
        sa = wave_reduce_sum(sa);
        cv = wave_reduce_sum(cv);
        bvo = wave_reduce_sum(bvo);
        if (lane == 0) { consts[32] = sa; consts[33] = cv + bvo; }
    }
}

// --- K5: main streaming. lane = 2 adjacent n (f32x2); 4 waves x 64 d;
// 2 blocks split the 512-d range (dhalf) -> partials in pbuf.
// y = scale*x + pe formed in-register; rows: S1=sum y, S2=sum y^2,
// acc[g]=sum A[g,d]*y. Packed math via f32x2 (v_pk_fma_f32), A broadcast
// from duplicated A2 (uniform addr -> s_load). Same op count as round 0
// (Sx pk_fma replaced by the y pk_fma); VGPR ~85, no spill at 128 cap.
__launch_bounds__(256, 4)
__global__ void main2_kernel(const float* __restrict__ latents,
                             const float* __restrict__ PET,
                             const f32x2* __restrict__ A2,
                             float* __restrict__ pbuf, int N) {
    int ntiles = N >> 7;                      // 128-n tiles
    int ntile = blockIdx.x % ntiles;
    int dh = blockIdx.x / ntiles;             // 0/1: which 256-d half
    int b = blockIdx.y;
    int lane = threadIdx.x & 63;
    int w = threadIdx.x >> 6;
    int n0 = ntile * 128 + lane * 2;

    int d0 = __builtin_amdgcn_readfirstlane(dh * 256 + w * 64);
    const float* latf = latents + (size_t)b * DM * N + (size_t)d0 * N + n0;
    const float* petf = PET + (size_t)d0 * N + n0;
    const float scale = 22.627416997969522f;
    f32x2 sc2; sc2.x = scale; sc2.y = scale;

    f32x2 acc[NG];
    #pragma unroll
    for (int i = 0; i < NG; ++i) { acc[i].x = 0.f; acc[i].y = 0.f; }
    f32x2 S1 = {0.f, 0.f}, S2 = {0.f, 0.f};

    const int U = 4;                 // d per chunk
    const int NC = 64 / U;           // 16 chunks
    f32x2 xb[2][U], pb[2][U];
    #pragma unroll
    for (int u = 0; u < U; ++u) {
        xb[0][u] = __builtin_nontemporal_load((const f32x2*)(latf + (size_t)u * N));
        pb[0][u] = *(const f32x2*)(petf + (size_t)u * N);
    }
    for (int c = 0; c < NC; c += 2) {         // explicit 2x unroll: cur/nxt static
        #pragma unroll
        for (int u = 0; u < U; ++u) {
            size_t dd = (size_t)((c + 1) * U + u) * N;
            xb[1][u] = __builtin_nontemporal_load((const f32x2*)(latf + dd));
            pb[1][u] = *(const f32x2*)(petf + dd);
        }
        #pragma unroll
        for (int u = 0; u < U; ++u) {
            f32x2 y = xb[0][u] * sc2 + pb[0][u];
            S1 += y; S2 += y * y;
            int d = d0 + c * U + u;
            #pragma unroll
            for (int q = 0; q < NG; ++q)
                acc[q] += A2[(size_t)q * DM + d] * y;
        }
        if (c + 2 < NC) {
            #pragma unroll
            for (int u = 0; u < U; ++u) {
                size_t dd = (size_t)((c + 2) * U + u) * N;
                xb[0][u] = __builtin_nontemporal_load((const f32x2*)(latf + dd));
                pb[0][u] = *(const f32x2*)(petf + dd);
            }
        }
        #pragma unroll
        for (int u = 0; u < U; ++u) {
            f32x2 y = xb[1][u] * sc2 + pb[1][u];
            S1 += y; S2 += y * y;
            int d = d0 + (c + 1) * U + u;
            #pragma unroll
            for (int q = 0; q < NG; ++q)
                acc[q] += A2[(size_t)q * DM + d] * y;
        }
    }

    __shared__ f32x2 red[4][NR][64];
    red[w][0][lane] = S1;
    red[w][1][lane] = S2;
    #pragma unroll
    for (int i = 0; i < NG; ++i) red[w][2 + i][lane] = acc[i];
    __syncthreads();
    if (w != 0) return;

    // pbuf[((dh*B + b)*NR + i)*N + n]
    float* pout = pbuf + (((size_t)dh * gridDim.y + b) * NR) * N + n0;
    #pragma unroll
    for (int i = 0; i < NR; ++i) {
        f32x2 t = red[0][i][lane] + red[1][i][lane] + red[2][i][lane] + red[3][i][lane];
        *(f32x2*)(pout + (size_t)i * N) = t;
    }
}

// --- K5b: finalize. one thread per n-pair: combine 2 d-halves, LN math,
// write vbuf + 16 score rows. (y-stats direct: no peA/peS/peQ terms) --------
__global__ void finalize_kernel(const float* __restrict__ pbuf,
                                const float* __restrict__ consts,
                                float* __restrict__ scores,
                                float* __restrict__ vbuf, int N, int B) {
    int t = blockIdx.x * 256 + threadIdx.x;
    int ppb = N >> 1;                        // n-pairs per batch
    int b = t / ppb;
    int n0 = (t - b * ppb) * 2;
    if (b >= B) return;

    const float* p0 = pbuf + (((size_t)0 * B + b) * NR) * N + n0;
    const float* p1 = pbuf + (((size_t)1 * B + b) * NR) * N + n0;
    f32x2 tot[NR];
    #pragma unroll
    for (int i = 0; i < NR; ++i)
        tot[i] = *(const f32x2*)(p0 + (size_t)i * N) + *(const f32x2*)(p1 + (size_t)i * N);

    f32x2 m = tot[0] * (1.f / DM);
    f32x2 ex2 = tot[1] * (1.f / DM);
    f32x2 rstd;
    rstd.x = rsqrtf(ex2.x - m.x * m.x + 1e-5f);
    rstd.y = rsqrtf(ex2.y - m.y * m.y + 1e-5f);

    float sumAv = consts[32], CvT = consts[33];
    f32x2 v = rstd * (tot[2 + NQ] - m * sumAv) + CvT;
    *(f32x2*)(vbuf + (size_t)b * N + n0) = v;

    const float isd = 0.044194173824159216f;  // 1/sqrt(512)
    #pragma unroll
    for (int q = 0; q < NQ; ++q) {
        f32x2 sc = (rstd * (tot[2 + q] - m * consts[q]) + consts[16 + q]) * isd;
        *(f32x2*)(scores + ((size_t)b * NQ + q) * N + n0) = sc;
    }
}

// --- K6: softmax, 4 rows per block (wave per row), float4 IO ---------------
__global__ void softmax_kernel(const float* __restrict__ scores,
                               const float* __restrict__ vbuf,
                               const float* __restrict__ query_mask,
                               const float* __restrict__ bo,
                               float* __restrict__ out_logits,
                               float* __restrict__ out_attn, int N) {
    int r = blockIdx.x * 4 + (threadIdx.x >> 6);   // b*NQ + q
    int b = r >> 4;
    int lane = threadIdx.x & 63;
    float4* attn_row = (float4*)(out_attn + (size_t)r * N);
    float qm = query_mask[r];
    int nv = N / 4;                     // float4 count per row
    if (qm == 0.f) {                    // fully masked row: uniform weights, wiped logits
        float u = 1.f / (float)N;
        float4 uv = make_float4(u, u, u, u);
        for (int i = lane; i < nv; i += 64) attn_row[i] = uv;
        if (lane == 0) out_logits[r] = bo[0];
        return;
    }
    const float4* srow = (const float4*)(scores + (size_t)r * N);
    float4 sv[2];
    sv[0] = srow[lane]; sv[1] = srow[64 + lane];
    float mx = fmaxf(fmaxf(fmaxf(sv[0].x, sv[0].y), fmaxf(sv[0].z, sv[0].w)),
                     fmaxf(fmaxf(sv[1].x, sv[1].y), fmaxf(sv[1].z, sv[1].w)));
    mx = wave_reduce_max(mx);
    float sum = 0.f;
    #pragma unroll
    for (int i = 0; i < 2; ++i) {
        sv[i].x = expf(sv[i].x - mx); sv[i].y = expf(sv[i].y - mx);
        sv[i].z = expf(sv[i].z - mx); sv[i].w = expf(sv[i].w - mx);
        sum += sv[i].x + sv[i].y + sv[i].z + sv[i].w;
    }
    sum = wave_reduce_sum(sum);
    float inv = 1.f / sum;
    const float4* vrow = (const float4*)(vbuf + (size_t)b * N);
    float lp = 0.f;
    #pragma unroll
    for (int i = 0; i < 2; ++i) {
        float4 vv = vrow[i * 64 + lane];
        float4 wgt;
        wgt.x = sv[i].x * inv; wgt.y = sv[i].y * inv;
        wgt.z = sv[i].z * inv; wgt.w = sv[i].w * inv;
        attn_row[i * 64 + lane] = wgt;
        lp += wgt.x * vv.x + wgt.y * vv.y + wgt.z * vv.z + wgt.w * vv.w;
    }
    lp = wave_reduce_sum(lp);
    if (lane == 0) out_logits[r] = lp + bo[0];
}

extern "C" void kernel_launch(void* const* d_in, const int* in_sizes, int n_in,
                              void* d_out, int out_size, void* d_ws, size_t ws_size,
                              hipStream_t stream) {
    const float* latents    = (const float*)d_in[0];
    const float* query_mask = (const float*)d_in[1];
    const float* query      = (const float*)d_in[2];
    const float* ln_lat_w   = (const float*)d_in[3];
    const float* ln_lat_b   = (const float*)d_in[4];
    const float* ln_q_w     = (const float*)d_in[5];
    const float* ln_q_b     = (const float*)d_in[6];
    const float* Wq         = (const float*)d_in[7];
    const float* bq         = (const float*)d_in[8];
    const float* Wk         = (const float*)d_in[9];
    const float* bk         = (const float*)d_in[10];
    const float* Wv         = (const float*)d_in[11];
    const float* bv         = (const float*)d_in[12];
    const float* Wo         = (const float*)d_in[13];
    const float* bo         = (const float*)d_in[14];

    int B = in_sizes[1] / NQ;
    int N = in_sizes[0] / (DM * B);

    float* ws = (float*)d_ws;
    size_t off = 0;
    float* PET    = ws + off; off += (size_t)DM * N;
    float* WkT    = ws + off; off += (size_t)DM * DM;
    float* WvT    = ws + off; off += (size_t)DM * DM;
    float* q_ln   = ws + off; off += NQ * DM;
    float* qh     = ws + off; off += NQ * DM;
    float* qt     = ws + off; off += NQ * DM;
    float* A      = ws + off; off += NG * DM;
    float* A2     = ws + off; off += (size_t)NG * DM * 2;
    float* wv     = ws + off; off += DM;
    float* consts = ws + off; off += 64;
    float* scores = ws + off; off += (size_t)B * NQ * N;
    float* vbuf   = ws + off; off += (size_t)B * N;
    float* pbuf   = ws + off; off += (size_t)2 * B * NR * N;

    float* out_logits = (float*)d_out;
    float* out_attn   = out_logits + (size_t)B * NQ;

    k1_setup<<<257, 256, 0, stream>>>(Wk, Wv, query, ln_q_w, ln_q_b,
                                      PET, WkT, WvT, q_ln, N);
    k2_qh<<<NQ * DM / 4, 256, 0, stream>>>(q_ln, Wq, bq, qh);
    k3_qt<<<NG * DM / 4, 256, 0, stream>>>(qh, WkT, Wo, WvT, ln_lat_w,
                                           qt, A, (f32x2*)A2, wv);
    k_consts<<<5, 256, 0, stream>>>(A, qt, qh, wv, ln_lat_b, bk, Wo, bv, consts);
    dim3 gmain((N >> 7) * 2, B);
    main2_kernel<<<gmain, 256, 0, stream>>>(latents, PET, (const f32x2*)A2,
                                            pbuf, N);
    int fin_threads = B * (N / 2);
    finalize_kernel<<<(fin_threads + 255) / 256, 256, 0, stream>>>(
        pbuf, consts, scores, vbuf, N, B);
    softmax_kernel<<<B * NQ / 4, 256, 0, stream>>>(scores, vbuf, query_mask, bo,
                                                   out_logits, out_attn, N);
}

// Round 3
// 240.881 us; speedup vs baseline: 1.1572x; 1.0197x over previous
//
#include <hip/hip_runtime.h>
#include <math.h>

#define DM 512          // d_model
#define NQ 16           // num output queries
#define NG (NQ + 1)     // 16 score rows + 1 pooled-v row
#define NR (NG + 2)     // 19 partial rows: S1, S2, acc[0..16]

typedef __attribute__((ext_vector_type(2))) float f32x2;

__device__ __forceinline__ float wave_reduce_sum(float v) {
    #pragma unroll
    for (int off = 32; off > 0; off >>= 1) v += __shfl_xor(v, off, 64);
    return v;
}
__device__ __forceinline__ float wave_reduce_max(float v) {
    #pragma unroll
    for (int off = 32; off > 0; off >>= 1) v = fmaxf(v, __shfl_xor(v, off, 64));
    return v;
}

// --- K1: fused independent precompute --------------------------------------
// blocks 0..127   : PET[d][n] generation (8 n-tiles x 16 j-groups)
// blocks 128..255 : LDS-tiled transpose Wk->WkT, Wv->WvT
// blocks 256..2303: qh[q][e] = LN(query[q]*scale) . Wq[e] + bq[e]
//                   (query-LN recomputed per wave in registers -> no q_ln
//                   dependency, lets this fuse with PET/transpose)
__global__ void k1_setup(const float* __restrict__ Wk, const float* __restrict__ Wv,
                         const float* __restrict__ query,
                         const float* __restrict__ ln_q_w, const float* __restrict__ ln_q_b,
                         const float* __restrict__ Wq, const float* __restrict__ bq,
                         float* __restrict__ PET, float* __restrict__ WkT,
                         float* __restrict__ WvT, float* __restrict__ qh, int N) {
    __shared__ float tile[64][65];
    int bx = blockIdx.x;
    int lane = threadIdx.x & 63;
    int w = threadIdx.x >> 6;

    if (bx < 128) {                       // --- PET ---
        int ntile = bx & 7, jg = bx >> 3;
        int n = ntile * 64 + lane;
        float p = (float)(N - 1 - n);     // reversed PE
        const float c = -logf(10000.f) / (float)DM;
        int jbase = jg * 16 + w * 4;
        #pragma unroll
        for (int u = 0; u < 4; ++u) {
            int j = jbase + u;
            float wj = expf((float)(2 * j) * c);
            float ang = p * wj;
            PET[(size_t)(2 * j) * N + n] = sinf(ang);
            PET[(size_t)(2 * j + 1) * N + n] = cosf(ang);
        }
    } else if (bx < 256) {                // --- transpose ---
        int t = bx - 128;
        const float* W = (t >> 6) ? Wv : Wk;
        float* WT = (t >> 6) ? WvT : WkT;
        int tl = t & 63;
        int te = tl >> 3, td = tl & 7;    // 8x8 tiles of 64x64
        #pragma unroll
        for (int i = 0; i < 16; ++i) {
            int el = w * 16 + i;
            tile[el][lane] = W[(size_t)(te * 64 + el) * DM + td * 64 + lane];
        }
        __syncthreads();
        #pragma unroll
        for (int i = 0; i < 16; ++i) {
            int dl = w * 16 + i;
            WT[(size_t)(td * 64 + dl) * DM + te * 64 + lane] = tile[lane][dl];
        }
    } else {                              // --- qh (one wave per (q,e)) ---
        int idx = (bx - 256) * 4 + w;     // 0..8191
        int q = idx >> 9, e = idx & 511;
        const float scale = 22.627416997969522f;   // sqrt(512)
        const float4* qr = (const float4*)(query + (size_t)q * DM);
        float4 a0 = qr[lane * 2], a1 = qr[lane * 2 + 1];
        a0.x *= scale; a0.y *= scale; a0.z *= scale; a0.w *= scale;
        a1.x *= scale; a1.y *= scale; a1.z *= scale; a1.w *= scale;
        float s  = a0.x + a0.y + a0.z + a0.w + a1.x + a1.y + a1.z + a1.w;
        float s2 = a0.x * a0.x + a0.y * a0.y + a0.z * a0.z + a0.w * a0.w
                 + a1.x * a1.x + a1.y * a1.y + a1.z * a1.z + a1.w * a1.w;
        s = wave_reduce_sum(s); s2 = wave_reduce_sum(s2);
        float m = s * (1.f / DM);
        float var = s2 * (1.f / DM) - m * m;
        float rstd = rsqrtf(var + 1e-5f);
        const float4* gw = (const float4*)ln_q_w;
        const float4* gb = (const float4*)ln_q_b;
        const float4* wr = (const float4*)(Wq + (size_t)e * DM);
        float4 w0 = gw[lane * 2], w1 = gw[lane * 2 + 1];
        float4 b0 = gb[lane * 2], b1 = gb[lane * 2 + 1];
        float4 W0 = wr[lane * 2], W1 = wr[lane * 2 + 1];
        float acc = ((a0.x - m) * rstd * w0.x + b0.x) * W0.x
                  + ((a0.y - m) * rstd * w0.y + b0.y) * W0.y
                  + ((a0.z - m) * rstd * w0.z + b0.z) * W0.z
                  + ((a0.w - m) * rstd * w0.w + b0.w) * W0.w
                  + ((a1.x - m) * rstd * w1.x + b1.x) * W1.x
                  + ((a1.y - m) * rstd * w1.y + b1.y) * W1.y
                  + ((a1.z - m) * rstd * w1.z + b1.z) * W1.z
                  + ((a1.w - m) * rstd * w1.w + b1.w) * W1.w;
        acc = wave_reduce_sum(acc);
        if (lane == 0) qh[q * DM + e] = acc + bq[e];
    }
}

// --- K3: qt[g][d] (g<16) and wv[d] (g=16) via contiguous WkT/WvT rows ------
//         A[g][d] = coeff * ln_lat_w[d]; A2 = duplicated pair for pk_fma ----
__global__ void k3_qt(const float* __restrict__ qh, const float* __restrict__ WkT,
                      const float* __restrict__ Wo, const float* __restrict__ WvT,
                      const float* __restrict__ lnw,
                      float* __restrict__ qt, float* __restrict__ A,
                      f32x2* __restrict__ A2, float* __restrict__ wvout) {
    int idx = blockIdx.x * 4 + (threadIdx.x >> 6);   // 0..8703
    int lane = threadIdx.x & 63;
    int g = idx >> 9, d = idx & 511;
    const float4* wr;
    const float4* xr;
    if (g < NQ) {
        wr = (const float4*)(WkT + (size_t)d * DM);
        xr = (const float4*)(qh + (size_t)g * DM);
    } else {
        wr = (const float4*)(WvT + (size_t)d * DM);
        xr = (const float4*)Wo;
    }
    float4 w0 = wr[lane * 2], w1 = wr[lane * 2 + 1];
    float4 x0 = xr[lane * 2], x1 = xr[lane * 2 + 1];
    float s = w0.x * x0.x + w0.y * x0.y + w0.z * x0.z + w0.w * x0.w
            + w1.x * x1.x + w1.y * x1.y + w1.z * x1.z + w1.w * x1.w;
    s = wave_reduce_sum(s);
    if (lane == 0) {
        if (g < NQ) qt[g * DM + d] = s;
        else wvout[d] = s;
        float a = s * lnw[d];
        A[g * DM + d] = a;
        f32x2 ap; ap.x = a; ap.y = a;
        A2[g * DM + d] = ap;
    }
}

// --- K5: main streaming + consts rider row ---------------------------------
// blockIdx.y < B : lane = 2 adjacent n (f32x2); 4 waves x 64 d; 2 blocks
//   split the 512-d range (dhalf) -> partials in pbuf. y = scale*x + pe
//   in-register; rows: S1=sum y, S2=sum y^2, acc[g]=sum A[g,d]*y.
// blockIdx.y == B: 8 rider blocks (5 active waves-tasks) compute consts —
//   deterministic k_consts fold, saves one serial launch.
__launch_bounds__(256, 4)
__global__ void main2_kernel(const float* __restrict__ latents,
                             const float* __restrict__ PET,
                             const f32x2* __restrict__ A2,
                             const float* __restrict__ A,
                             const float* __restrict__ qt,
                             const float* __restrict__ qh,
                             const float* __restrict__ wv,
                             const float* __restrict__ lnb,
                             const float* __restrict__ bk,
                             const float* __restrict__ Wo,
                             const float* __restrict__ bv,
                             float* __restrict__ pbuf,
                             float* __restrict__ consts, int N) {
    int B = gridDim.y - 1;
    int lane = threadIdx.x & 63;
    int w = threadIdx.x >> 6;
    int b = blockIdx.y;

    if (b == B) {                         // --- consts rider ---
        int t = blockIdx.x * 4 + w;       // 0..31, valid 0..16
        if (t > NQ) return;
        if (t < NQ) {
            float sa = 0.f, sc = 0.f, qb = 0.f;
            #pragma unroll
            for (int i = 0; i < 8; ++i) {
                int d = i * 64 + lane;
                sa += A[t * DM + d];
                sc = fmaf(qt[t * DM + d], lnb[d], sc);
                qb = fmaf(qh[t * DM + d], bk[d], qb);
            }
            sa = wave_reduce_sum(sa);
            sc = wave_reduce_sum(sc);
            qb = wave_reduce_sum(qb);
            if (lane == 0) { consts[t] = sa; consts[16 + t] = sc + qb; }
        } else {
            float sa = 0.f, cv = 0.f, bvo = 0.f;
            #pragma unroll
            for (int i = 0; i < 8; ++i) {
                int d = i * 64 + lane;
                sa += A[NQ * DM + d];
                cv = fmaf(wv[d], lnb[d], cv);
                bvo = fmaf(Wo[d], bv[d], bvo);
            }
            sa = wave_reduce_sum(sa);
            cv = wave_reduce_sum(cv);
            bvo = wave_reduce_sum(bvo);
            if (lane == 0) { consts[32] = sa; consts[33] = cv + bvo; }
        }
        return;
    }

    int ntiles = N >> 7;                      // 128-n tiles
    int ntile = blockIdx.x % ntiles;
    int dh = blockIdx.x / ntiles;             // 0/1: which 256-d half
    int n0 = ntile * 128 + lane * 2;

    int d0 = __builtin_amdgcn_readfirstlane(dh * 256 + w * 64);
    const float* latf = latents + (size_t)b * DM * N + (size_t)d0 * N + n0;
    const float* petf = PET + (size_t)d0 * N + n0;
    const float scale = 22.627416997969522f;
    f32x2 sc2; sc2.x = scale; sc2.y = scale;

    f32x2 acc[NG];
    #pragma unroll
    for (int i = 0; i < NG; ++i) { acc[i].x = 0.f; acc[i].y = 0.f; }
    f32x2 S1 = {0.f, 0.f}, S2 = {0.f, 0.f};

    const int U = 4;                 // d per chunk
    const int NC = 64 / U;           // 16 chunks
    f32x2 xb[2][U], pb[2][U];
    #pragma unroll
    for (int u = 0; u < U; ++u) {
        xb[0][u] = __builtin_nontemporal_load((const f32x2*)(latf + (size_t)u * N));
        pb[0][u] = *(const f32x2*)(petf + (size_t)u * N);
    }
    for (int c = 0; c < NC; c += 2) {         // explicit 2x unroll: cur/nxt static
        #pragma unroll
        for (int u = 0; u < U; ++u) {
            size_t dd = (size_t)((c + 1) * U + u) * N;
            xb[1][u] = __builtin_nontemporal_load((const f32x2*)(latf + dd));
            pb[1][u] = *(const f32x2*)(petf + dd);
        }
        #pragma unroll
        for (int u = 0; u < U; ++u) {
            f32x2 y = xb[0][u] * sc2 + pb[0][u];
            S1 += y; S2 += y * y;
            int d = d0 + c * U + u;
            #pragma unroll
            for (int q = 0; q < NG; ++q)
                acc[q] += A2[(size_t)q * DM + d] * y;
        }
        if (c + 2 < NC) {
            #pragma unroll
            for (int u = 0; u < U; ++u) {
                size_t dd = (size_t)((c + 2) * U + u) * N;
                xb[0][u] = __builtin_nontemporal_load((const f32x2*)(latf + dd));
                pb[0][u] = *(const f32x2*)(petf + dd);
            }
        }
        #pragma unroll
        for (int u = 0; u < U; ++u) {
            f32x2 y = xb[1][u] * sc2 + pb[1][u];
            S1 += y; S2 += y * y;
            int d = d0 + (c + 1) * U + u;
            #pragma unroll
            for (int q = 0; q < NG; ++q)
                acc[q] += A2[(size_t)q * DM + d] * y;
        }
    }

    __shared__ f32x2 red[4][NR][64];
    red[w][0][lane] = S1;
    red[w][1][lane] = S2;
    #pragma unroll
    for (int i = 0; i < NG; ++i) red[w][2 + i][lane] = acc[i];
    __syncthreads();
    if (w != 0) return;

    // pbuf[((dh*B + b)*NR + i)*N + n]
    float* pout = pbuf + (((size_t)dh * B + b) * NR) * N + n0;
    #pragma unroll
    for (int i = 0; i < NR; ++i) {
        f32x2 t = red[0][i][lane] + red[1][i][lane] + red[2][i][lane] + red[3][i][lane];
        *(f32x2*)(pout + (size_t)i * N) = t;
    }
}

// --- K6: fused finalize + softmax, one block per batch b --------------------
// phase 1: per n-pair combine 2 d-halves + LN math -> scores/v rows in LDS
// phase 2: wave-per-row softmax from LDS (16B/lane contiguous ds_read_b128,
//          conflict-free), write attn + logits. Kills scores/vbuf HBM trip.
__global__ void k_fin(const float* __restrict__ pbuf,
                      const float* __restrict__ consts,
                      const float* __restrict__ query_mask,
                      const float* __restrict__ bo,
                      float* __restrict__ out_logits,
                      float* __restrict__ out_attn, int N, int B) {
    __shared__ float scs[NQ][512];
    __shared__ float vls[512];
    int b = blockIdx.x;
    int tid = threadIdx.x;
    const float isd = 0.044194173824159216f;  // 1/sqrt(512)
    float c32 = consts[32], c33 = consts[33];

    for (int np = tid; np < (N >> 1); np += 256) {
        int n0 = np * 2;
        const float* p0 = pbuf + (((size_t)0 * B + b) * NR) * N + n0;
        const float* p1 = pbuf + (((size_t)1 * B + b) * NR) * N + n0;
        f32x2 tot[NR];
        #pragma unroll
        for (int i = 0; i < NR; ++i)
            tot[i] = *(const f32x2*)(p0 + (size_t)i * N)
                   + *(const f32x2*)(p1 + (size_t)i * N);
        f32x2 m = tot[0] * (1.f / DM);
        f32x2 ex2 = tot[1] * (1.f / DM);
        f32x2 rstd;
        rstd.x = rsqrtf(ex2.x - m.x * m.x + 1e-5f);
        rstd.y = rsqrtf(ex2.y - m.y * m.y + 1e-5f);
        f32x2 v = rstd * (tot[2 + NQ] - m * c32) + c33;
        *(f32x2*)&vls[n0] = v;
        #pragma unroll
        for (int q = 0; q < NQ; ++q) {
            f32x2 sc = (rstd * (tot[2 + q] - m * consts[q]) + consts[16 + q]) * isd;
            *(f32x2*)&scs[q][n0] = sc;
        }
    }
    __syncthreads();

    int lane = tid & 63, w = tid >> 6;
    int nv = N >> 2;                      // float4 count per row
    for (int q = w; q < NQ; q += 4) {
        int r = b * NQ + q;
        float qm = query_mask[r];
        float4* arow = (float4*)(out_attn + (size_t)r * N);
        if (qm == 0.f) {                  // fully masked: uniform weights, wiped logits
            float u = 1.f / (float)N;
            float4 uv = make_float4(u, u, u, u);
            for (int i = lane; i < nv; i += 64) arow[i] = uv;
            if (lane == 0) out_logits[r] = bo[0];
            continue;
        }
        const float4* srow = (const float4*)scs[q];
        float4 sv[2];
        sv[0] = srow[lane]; sv[1] = srow[64 + lane];
        float mx = fmaxf(fmaxf(fmaxf(sv[0].x, sv[0].y), fmaxf(sv[0].z, sv[0].w)),
                         fmaxf(fmaxf(sv[1].x, sv[1].y), fmaxf(sv[1].z, sv[1].w)));
        mx = wave_reduce_max(mx);
        float sum = 0.f;
        #pragma unroll
        for (int i = 0; i < 2; ++i) {
            sv[i].x = expf(sv[i].x - mx); sv[i].y = expf(sv[i].y - mx);
            sv[i].z = expf(sv[i].z - mx); sv[i].w = expf(sv[i].w - mx);
            sum += sv[i].x + sv[i].y + sv[i].z + sv[i].w;
        }
        sum = wave_reduce_sum(sum);
        float inv = 1.f / sum;
        const float4* vrow = (const float4*)vls;
        float lp = 0.f;
        #pragma unroll
        for (int i = 0; i < 2; ++i) {
            float4 vv = vrow[i * 64 + lane];
            float4 wgt;
            wgt.x = sv[i].x * inv; wgt.y = sv[i].y * inv;
            wgt.z = sv[i].z * inv; wgt.w = sv[i].w * inv;
            arow[i * 64 + lane] = wgt;
            lp += wgt.x * vv.x + wgt.y * vv.y + wgt.z * vv.z + wgt.w * vv.w;
        }
        lp = wave_reduce_sum(lp);
        if (lane == 0) out_logits[r] = lp + bo[0];
    }
}

extern "C" void kernel_launch(void* const* d_in, const int* in_sizes, int n_in,
                              void* d_out, int out_size, void* d_ws, size_t ws_size,
                              hipStream_t stream) {
    const float* latents    = (const float*)d_in[0];
    const float* query_mask = (const float*)d_in[1];
    const float* query      = (const float*)d_in[2];
    const float* ln_lat_w   = (const float*)d_in[3];
    const float* ln_lat_b   = (const float*)d_in[4];
    const float* ln_q_w     = (const float*)d_in[5];
    const float* ln_q_b     = (const float*)d_in[6];
    const float* Wq         = (const float*)d_in[7];
    const float* bq         = (const float*)d_in[8];
    const float* Wk         = (const float*)d_in[9];
    const float* bk         = (const float*)d_in[10];
    const float* Wv         = (const float*)d_in[11];
    const float* bv         = (const float*)d_in[12];
    const float* Wo         = (const float*)d_in[13];
    const float* bo         = (const float*)d_in[14];

    int B = in_sizes[1] / NQ;
    int N = in_sizes[0] / (DM * B);

    float* ws = (float*)d_ws;
    size_t off = 0;
    float* PET    = ws + off; off += (size_t)DM * N;
    float* WkT    = ws + off; off += (size_t)DM * DM;
    float* WvT    = ws + off; off += (size_t)DM * DM;
    float* qh     = ws + off; off += NQ * DM;
    float* qt     = ws + off; off += NQ * DM;
    float* A      = ws + off; off += NG * DM;
    float* A2     = ws + off; off += (size_t)NG * DM * 2;
    float* wv     = ws + off; off += DM;
    float* consts = ws + off; off += 64;
    float* pbuf   = ws + off; off += (size_t)2 * B * NR * N;

    float* out_logits = (float*)d_out;
    float* out_attn   = out_logits + (size_t)B * NQ;

    k1_setup<<<256 + NQ * DM / 4, 256, 0, stream>>>(
        Wk, Wv, query, ln_q_w, ln_q_b, Wq, bq, PET, WkT, WvT, qh, N);
    k3_qt<<<NG * DM / 4, 256, 0, stream>>>(qh, WkT, Wo, WvT, ln_lat_w,
                                           qt, A, (f32x2*)A2, wv);
    dim3 gmain((N >> 7) * 2, B + 1);
    main2_kernel<<<gmain, 256, 0, stream>>>(latents, PET, (const f32x2*)A2,
                                            A, qt, qh, wv, ln_lat_b, bk, Wo, bv,
                                            pbuf, consts, N);
    k_fin<<<B, 256, 0, stream>>>(pbuf, consts, query_mask, bo,
                                 out_logits, out_attn, N, B);
}